// Round 5
// baseline (78.861 us; speedup 1.0000x reference)
//
#include <hip/hip_runtime.h>
#include <math.h>

// M is (64, 512, 28, 28) fp32.
#define BB 64
#define CC 512
#define HWP 784                 // px per map
#define NF4 196                 // float4 groups per map
#define NCHUNK 16               // channel chunks (32 ch each)
#define NPIX4 12544             // (64*784)/4 float4 pixel-groups
#define PLANE4 200704           // NCHUNK * NPIX4 float4 per plane
#define DIS_SLOTS 4096          // 64 b * 16 chunks * 4 waves
#define DIV_SLOTS 196
#define NEG_FILL -999999.0f
#define NTOT 25690112.0         // 64*512*28*28

static __device__ __forceinline__ unsigned sortable(float v) {
  unsigned b = __float_as_uint(v);
  return (b & 0x80000000u) ? ~b : (b | 0x80000000u);
}
// branchless top-2 insert
static __device__ __forceinline__ void top2(float v, float& v1, float& v2) {
  float lo = fminf(v, v1);
  v1 = fmaxf(v1, v);
  v2 = fmaxf(v2, lo);
}
// merge two (v1>=v2) pairs
static __device__ __forceinline__ void mergev(float& v1, float& v2, float b1, float b2) {
  float lo = fminf(v1, b1);
  v1 = fmaxf(v1, b1);
  v2 = fmaxf(lo, fmaxf(v2, b2));
}
static __device__ __forceinline__ void mergev4(float4& v1, float4& v2, float4 b1, float4 b2) {
  mergev(v1.x, v2.x, b1.x, b2.x);
  mergev(v1.y, v2.y, b1.y, b2.y);
  mergev(v1.z, v2.z, b1.z, b2.z);
  mergev(v1.w, v2.w, b1.w, b2.w);
}

// per-channel consume body (float4 group at pxb, geometry fy/fx*/rr*)
#define CHBODY(c) {                                                          \
    float a0 = d[c].x, a1 = d[c].y, a2 = d[c].z, a3 = d[c].w;                \
    float q0 = a0, q1 = a1, q2 = a2, q3 = a3;                                \
    if (fake) { a0 = a1 = a2 = a3 = 0.f;                                     \
                q0 = q1 = q2 = q3 = -INFINITY; }                             \
    const float sum4 = (a0 + a1) + (a2 + a3);                                \
    s0[c] += sum4;                                                           \
    sy[c] = fmaf(sum4, fy, sy[c]);                                           \
    sx[c] = fmaf(a0, fx0, sx[c]); sx[c] = fmaf(a1, fx1, sx[c]);              \
    sx[c] = fmaf(a2, fx2, sx[c]); sx[c] = fmaf(a3, fx3, sx[c]);              \
    srr = fmaf(a0, rr0, srr); srr = fmaf(a1, rr1, srr);                      \
    srr = fmaf(a2, rr2, srr); srr = fmaf(a3, rr3, srr);                      \
    if (q0 > bv[c]) { bv[c] = q0; bi[c] = pxb;     }                         \
    if (q1 > bv[c]) { bv[c] = q1; bi[c] = pxb + 1; }                         \
    if (q2 > bv[c]) { bv[c] = q2; bi[c] = pxb + 2; }                         \
    if (q3 > bv[c]) { bv[c] = q3; bi[c] = pxb + 3; }                         \
    top2(q0, v1.x, v2.x); S.x += a0;                                         \
    top2(q1, v1.y, v2.y); S.y += a1;                                         \
    top2(q2, v1.z, v2.z); S.z += a2;                                         \
    top2(q3, v1.w, v2.w); S.w += a3; }

#define GEOM(f)                                                              \
    const int y = (f) / 7;                                                   \
    const float fy  = (float)y;                                              \
    const float fx0 = (float)(((f) - y * 7) * 4);                            \
    const float fx1 = fx0 + 1.f, fx2 = fx0 + 2.f, fx3 = fx0 + 3.f;           \
    const float fyy = fy * fy;                                               \
    const float rr0 = fyy + fx0 * fx0, rr1 = fyy + fx1 * fx1;                \
    const float rr2 = fyy + fx2 * fx2, rr3 = fyy + fx3 * fx3;                \
    const int pxb = (f) * 4;

// ---------------- fused single-pass kernel ----------------
// block = (chunk, b): 32 ch x 784 px; 4 waves, 8 ch/wave. float4 passes
// 0..2 uniform + masked tail; rolling half-pass prefetch (d[8] + dn[4]).
__global__ __launch_bounds__(256, 4) void fused_kernel(const float* __restrict__ M,
    double* __restrict__ slots, float4* __restrict__ wsV1, float4* __restrict__ wsV2,
    float4* __restrict__ wsS, unsigned* __restrict__ counter) {
  const int lane  = threadIdx.x & 63;
  const int w     = threadIdx.x >> 6;
  const int chunk = blockIdx.x;
  const int b     = blockIdx.y;
  if (chunk == 0 && b == 0 && threadIdx.x == 0) *counter = 0u;   // for div_merge

  const float4* base4 =
      (const float4*)(M + ((size_t)b * CC + chunk * 32 + w * 8) * HWP);

  float s0[8], sy[8], sx[8], bv[8];
  int bi[8];
  #pragma unroll
  for (int c = 0; c < 8; ++c) { s0[c]=0.f; sy[c]=0.f; sx[c]=0.f; bv[c]=-INFINITY; bi[c]=0; }
  float srr = 0.f;                          // sum M*(y^2+x^2), lane slice

  __shared__ float4 lm[4][3][NF4];          // per-wave per-pixel (v1,v2,S)

  float4 d[8], dn[4];
  #pragma unroll
  for (int c = 0; c < 8; ++c) d[c] = base4[c * NF4 + lane];     // pass-0 loads

  const int tailf = (lane < 4) ? (192 + lane) : 195;            // clamped tail group

  #pragma unroll
  for (int k = 0; k < 3; ++k) {
    const int f  = lane + 64 * k;
    const int nf = (k == 2) ? tailf : (lane + 64 * (k + 1));
    const bool fake = false;
    GEOM(f)
    float4 v1 = make_float4(-INFINITY, -INFINITY, -INFINITY, -INFINITY);
    float4 v2 = v1;
    float4 S  = make_float4(0.f, 0.f, 0.f, 0.f);
    #pragma unroll
    for (int c = 0; c < 4; ++c) dn[c] = base4[c * NF4 + nf];    // prefetch A-half
    CHBODY(4) CHBODY(5) CHBODY(6) CHBODY(7)                      // consume B-half
    #pragma unroll
    for (int c = 4; c < 8; ++c) d[c] = base4[c * NF4 + nf];     // refill B-half
    CHBODY(0) CHBODY(1) CHBODY(2) CHBODY(3)                      // consume A-half
    #pragma unroll
    for (int c = 0; c < 4; ++c) d[c] = dn[c];                   // rotate A-half
    lm[w][0][f] = v1; lm[w][1][f] = v2; lm[w][2][f] = S;
  }
  { // masked-uniform tail pass (groups 192..195 real on lanes 0..3)
    const int f = tailf;
    const bool fake = (lane >= 4);
    GEOM(f)
    float4 v1 = make_float4(-INFINITY, -INFINITY, -INFINITY, -INFINITY);
    float4 v2 = v1;
    float4 S  = make_float4(0.f, 0.f, 0.f, 0.f);
    CHBODY(0) CHBODY(1) CHBODY(2) CHBODY(3)
    CHBODY(4) CHBODY(5) CHBODY(6) CHBODY(7)
    if (!fake) { lm[w][0][f] = v1; lm[w][1][f] = v2; lm[w][2][f] = S; }
  }

  // ---- dis epilogue: per-channel argmax butterfly, lane-local contribution ----
  double dis_acc = (double)srr;
  #pragma unroll
  for (int c = 0; c < 8; ++c) {
    unsigned long long key =
        ((unsigned long long)sortable(bv[c]) << 32) | (unsigned)(~bi[c]);
    #pragma unroll
    for (int off = 1; off < 64; off <<= 1) {
      unsigned long long o = __shfl_xor(key, off);
      key = (key > o) ? key : o;            // max val; tie -> min px
    }
    const int px = (int)(~((unsigned)key));
    const int iy = px / 28;
    const int ix = px - iy * 28;
    dis_acc += (double)s0[c] * (double)(iy * iy + ix * ix)
             - 2.0 * ((double)sy[c] * (double)iy + (double)sx[c] * (double)ix);
  }
  #pragma unroll
  for (int off = 32; off >= 1; off >>= 1)
    dis_acc += __shfl_down(dis_acc, off);
  if (lane == 0)
    slots[((b * NCHUNK + chunk) << 2) | w] = dis_acc;           // unique slot

  // ---- cross-wave merge of per-pixel top-2 partials ----
  __syncthreads();
  const int t = threadIdx.x;
  if (t < NF4) {
    float4 mv1 = lm[0][0][t], mv2 = lm[0][1][t], mS = lm[0][2][t];
    #pragma unroll
    for (int ww = 1; ww < 4; ++ww) {
      mergev4(mv1, mv2, lm[ww][0][t], lm[ww][1][t]);
      float4 bS = lm[ww][2][t];
      mS.x += bS.x; mS.y += bS.y; mS.z += bS.z; mS.w += bS.w;
    }
    const int idx = chunk * NPIX4 + b * NF4 + t;
    wsV1[idx] = mv1; wsV2[idx] = mv2; wsS[idx] = mS;
  }
}

// ---------------- merge chunk partials -> div; last block finalizes ----------------
__global__ __launch_bounds__(256) void div_merge_kernel(const float4* __restrict__ wsV1,
    const float4* __restrict__ wsV2, const float4* __restrict__ wsS,
    double* __restrict__ slots, unsigned* __restrict__ counter,
    float* __restrict__ out) {
  const int t = threadIdx.x, lane = t & 63, w = t >> 6;
  const int g = blockIdx.x * 64 + lane;

  float4 a1[4], a2[4], aS[4];
  #pragma unroll
  for (int c = 0; c < 4; ++c) {
    const int idx = (w * 4 + c) * NPIX4 + g;
    a1[c] = wsV1[idx]; a2[c] = wsV2[idx]; aS[c] = wsS[idx];
  }
  float4 v1 = a1[0], v2 = a2[0], S = aS[0];
  #pragma unroll
  for (int c = 1; c < 4; ++c) {
    mergev4(v1, v2, a1[c], a2[c]);
    S.x += aS[c].x; S.y += aS[c].y; S.z += aS[c].z; S.w += aS[c].w;
  }
  __shared__ float4 sm[4][3][64];
  sm[w][0][lane] = v1; sm[w][1][lane] = v2; sm[w][2][lane] = S;
  __syncthreads();

  if (t < 64) {
    v1 = sm[0][0][t]; v2 = sm[0][1][t]; S = sm[0][2][t];
    #pragma unroll
    for (int ww = 1; ww < 4; ++ww) {
      mergev4(v1, v2, sm[ww][0][t], sm[ww][1][t]);
      float4 bS = sm[ww][2][t];
      S.x += bS.x; S.y += bS.y; S.z += bS.z; S.w += bS.w;
    }
    // sum_c loo_c*M_c = clamp(v1)*(S - v1) + clamp(v2)*v1  (per pixel)
    double contrib =
        (double)fmaxf(v1.x, NEG_FILL) * ((double)S.x - (double)v1.x) + (double)fmaxf(v2.x, NEG_FILL) * (double)v1.x
      + (double)fmaxf(v1.y, NEG_FILL) * ((double)S.y - (double)v1.y) + (double)fmaxf(v2.y, NEG_FILL) * (double)v1.y
      + (double)fmaxf(v1.z, NEG_FILL) * ((double)S.z - (double)v1.z) + (double)fmaxf(v2.z, NEG_FILL) * (double)v1.z
      + (double)fmaxf(v1.w, NEG_FILL) * ((double)S.w - (double)v1.w) + (double)fmaxf(v2.w, NEG_FILL) * (double)v1.w;
    #pragma unroll
    for (int off = 32; off >= 1; off >>= 1)
      contrib += __shfl_down(contrib, off);
    if (t == 0)
      slots[DIS_SLOTS + blockIdx.x] = contrib;
  }

  // ---- last-block finalize (ticket) ----
  __shared__ unsigned ticket_s;
  __threadfence();
  __syncthreads();
  if (t == 0) ticket_s = atomicAdd(counter, 1u);
  __syncthreads();
  if (ticket_s == DIV_SLOTS - 1) {
    __threadfence();
    double dis = 0.0;
    #pragma unroll
    for (int i = 0; i < 16; ++i) dis += slots[t + (i << 8)];
    double dv = (t < DIV_SLOTS) ? slots[DIS_SLOTS + t] : 0.0;
    #pragma unroll
    for (int off = 32; off >= 1; off >>= 1) {
      dis += __shfl_down(dis, off);
      dv  += __shfl_down(dv,  off);
    }
    __shared__ double pd[4], pv[4];
    if (lane == 0) { pd[w] = dis; pv[w] = dv; }
    __syncthreads();
    if (t == 0) {
      out[0] = (float)((pd[0] + pd[1] + pd[2] + pd[3]) / NTOT);
      out[1] = (float)((pv[0] + pv[1] + pv[2] + pv[3]) / NTOT);
    }
  }
}

extern "C" void kernel_launch(void* const* d_in, const int* in_sizes, int n_in,
                              void* d_out, int out_size, void* d_ws, size_t ws_size,
                              hipStream_t stream) {
  const float* M = (const float*)d_in[0];
  double*   slots   = (double*)d_ws;                        // 4292 doubles
  unsigned* counter = (unsigned*)((char*)d_ws + 40960);
  float4*   planes  = (float4*)((char*)d_ws + 65536);       // 3 planes of PLANE4 float4
  float4* wsV1 = planes;
  float4* wsV2 = planes + PLANE4;
  float4* wsS  = planes + 2 * (size_t)PLANE4;
  fused_kernel<<<dim3(NCHUNK, BB), 256, 0, stream>>>(M, slots, wsV1, wsV2, wsS, counter);
  div_merge_kernel<<<DIV_SLOTS, 256, 0, stream>>>(wsV1, wsV2, wsS, slots, counter,
                                                  (float*)d_out);
}

// Round 6
// 77.455 us; speedup vs baseline: 1.0181x; 1.0181x over previous
//
#include <hip/hip_runtime.h>
#include <math.h>

// M is (64, 512, 28, 28) fp32.
#define BB 64
#define CC 512
#define HWP 784                 // px per map
#define NF4 196                 // float4 groups per map
#define NCHUNK 16               // channel chunks (32 ch each)
#define NPIX4 12544             // (64*784)/4 float4 pixel-groups
#define PLANE4 200704           // NCHUNK * NPIX4 float4 per plane
#define DIS_SLOTS 4096          // 64 b * 16 chunks * 4 waves
#define DIV_SLOTS 196
#define NEG_FILL -999999.0f
#define NTOT 25690112.0         // 64*512*28*28

static __device__ __forceinline__ unsigned sortable(float v) {
  unsigned b = __float_as_uint(v);
  return (b & 0x80000000u) ? ~b : (b | 0x80000000u);
}
// branchless top-2 insert
static __device__ __forceinline__ void top2(float v, float& v1, float& v2) {
  float lo = fminf(v, v1);
  v1 = fmaxf(v1, v);
  v2 = fmaxf(v2, lo);
}
// merge two (v1>=v2) pairs
static __device__ __forceinline__ void mergev(float& v1, float& v2, float b1, float b2) {
  float lo = fminf(v1, b1);
  v1 = fmaxf(v1, b1);
  v2 = fmaxf(lo, fmaxf(v2, b2));
}
static __device__ __forceinline__ void mergev4(float4& v1, float4& v2, float4 b1, float4 b2) {
  mergev(v1.x, v2.x, b1.x, b2.x);
  mergev(v1.y, v2.y, b1.y, b2.y);
  mergev(v1.z, v2.z, b1.z, b2.z);
  mergev(v1.w, v2.w, b1.w, b2.w);
}

// per-channel consume body (float4 group at pxb, geometry fy/fx*/rr*)
#define CHBODY(c) {                                                          \
    float a0 = d[c].x, a1 = d[c].y, a2 = d[c].z, a3 = d[c].w;                \
    float q0 = a0, q1 = a1, q2 = a2, q3 = a3;                                \
    if (fake) { a0 = a1 = a2 = a3 = 0.f;                                     \
                q0 = q1 = q2 = q3 = -INFINITY; }                             \
    const float sum4 = (a0 + a1) + (a2 + a3);                                \
    s0[c] += sum4;                                                           \
    sy[c] = fmaf(sum4, fy, sy[c]);                                           \
    sx[c] = fmaf(a0, fx0, sx[c]); sx[c] = fmaf(a1, fx1, sx[c]);              \
    sx[c] = fmaf(a2, fx2, sx[c]); sx[c] = fmaf(a3, fx3, sx[c]);              \
    srr = fmaf(a0, rr0, srr); srr = fmaf(a1, rr1, srr);                      \
    srr = fmaf(a2, rr2, srr); srr = fmaf(a3, rr3, srr);                      \
    if (q0 > bv[c]) { bv[c] = q0; bi[c] = pxb;     }                         \
    if (q1 > bv[c]) { bv[c] = q1; bi[c] = pxb + 1; }                         \
    if (q2 > bv[c]) { bv[c] = q2; bi[c] = pxb + 2; }                         \
    if (q3 > bv[c]) { bv[c] = q3; bi[c] = pxb + 3; }                         \
    top2(q0, v1.x, v2.x); S.x += a0;                                         \
    top2(q1, v1.y, v2.y); S.y += a1;                                         \
    top2(q2, v1.z, v2.z); S.z += a2;                                         \
    top2(q3, v1.w, v2.w); S.w += a3; }

#define GEOM(f)                                                              \
    const int y = (f) / 7;                                                   \
    const float fy  = (float)y;                                              \
    const float fx0 = (float)(((f) - y * 7) * 4);                            \
    const float fx1 = fx0 + 1.f, fx2 = fx0 + 2.f, fx3 = fx0 + 3.f;           \
    const float fyy = fy * fy;                                               \
    const float rr0 = fyy + fx0 * fx0, rr1 = fyy + fx1 * fx1;                \
    const float rr2 = fyy + fx2 * fx2, rr3 = fyy + fx3 * fx3;                \
    const int pxb = (f) * 4;

// ---------------- fused single-pass kernel ----------------
// block = (chunk, b): 32 ch x 784 px; 4 waves, 8 ch/wave. float4 passes
// 0..2 uniform + masked tail; full dn[8] prefetch in two half-interleaves.
// VGPR budget 128 (4 waves/EU): ~115 live regs, no spill. LDS 37.6 KB -> 4 blk/CU.
__global__ __launch_bounds__(256)
__attribute__((amdgpu_waves_per_eu(4)))
void fused_kernel(const float* __restrict__ M,
    double* __restrict__ slots, float4* __restrict__ wsV1, float4* __restrict__ wsV2,
    float4* __restrict__ wsS, unsigned* __restrict__ counter) {
  const int lane  = threadIdx.x & 63;
  const int w     = threadIdx.x >> 6;
  const int chunk = blockIdx.x;
  const int b     = blockIdx.y;
  if (chunk == 0 && b == 0 && threadIdx.x == 0) *counter = 0u;   // for div_merge ticket

  const float4* base4 =
      (const float4*)(M + ((size_t)b * CC + chunk * 32 + w * 8) * HWP);

  float s0[8], sy[8], sx[8], bv[8];
  int bi[8];
  #pragma unroll
  for (int c = 0; c < 8; ++c) { s0[c]=0.f; sy[c]=0.f; sx[c]=0.f; bv[c]=-INFINITY; bi[c]=0; }
  float srr = 0.f;                          // sum M*(y^2+x^2), lane slice

  __shared__ float4 lm[4][3][NF4];          // per-wave per-pixel (v1,v2,S)

  float4 d[8], dn[8];
  #pragma unroll
  for (int c = 0; c < 8; ++c) d[c] = base4[c * NF4 + lane];     // pass-0 loads

  const int tailf = (lane < 4) ? (192 + lane) : 195;            // clamped tail group

  #pragma unroll
  for (int k = 0; k < 3; ++k) {
    const int f  = lane + 64 * k;
    const int nf = (k == 2) ? tailf : (lane + 64 * (k + 1));
    const bool fake = false;
    GEOM(f)
    float4 v1 = make_float4(-INFINITY, -INFINITY, -INFINITY, -INFINITY);
    float4 v2 = v1;
    float4 S  = make_float4(0.f, 0.f, 0.f, 0.f);
    #pragma unroll
    for (int c = 0; c < 4; ++c) dn[c] = base4[c * NF4 + nf];    // issue next A-half
    CHBODY(4) CHBODY(5) CHBODY(6) CHBODY(7)                      // consume B-half
    #pragma unroll
    for (int c = 4; c < 8; ++c) dn[c] = base4[c * NF4 + nf];    // issue next B-half
    CHBODY(0) CHBODY(1) CHBODY(2) CHBODY(3)                      // consume A-half
    #pragma unroll
    for (int c = 0; c < 8; ++c) d[c] = dn[c];                   // rotate
    lm[w][0][f] = v1; lm[w][1][f] = v2; lm[w][2][f] = S;
  }
  { // masked-uniform tail pass (groups 192..195 real on lanes 0..3)
    const int f = tailf;
    const bool fake = (lane >= 4);
    GEOM(f)
    float4 v1 = make_float4(-INFINITY, -INFINITY, -INFINITY, -INFINITY);
    float4 v2 = v1;
    float4 S  = make_float4(0.f, 0.f, 0.f, 0.f);
    CHBODY(0) CHBODY(1) CHBODY(2) CHBODY(3)
    CHBODY(4) CHBODY(5) CHBODY(6) CHBODY(7)
    if (!fake) { lm[w][0][f] = v1; lm[w][1][f] = v2; lm[w][2][f] = S; }
  }

  // ---- dis epilogue: per-channel argmax butterfly, lane-local contribution ----
  double dis_acc = (double)srr;
  #pragma unroll
  for (int c = 0; c < 8; ++c) {
    unsigned long long key =
        ((unsigned long long)sortable(bv[c]) << 32) | (unsigned)(~bi[c]);
    #pragma unroll
    for (int off = 1; off < 64; off <<= 1) {
      unsigned long long o = __shfl_xor(key, off);
      key = (key > o) ? key : o;            // max val; tie -> min px
    }
    const int px = (int)(~((unsigned)key));
    const int iy = px / 28;
    const int ix = px - iy * 28;
    dis_acc += (double)s0[c] * (double)(iy * iy + ix * ix)
             - 2.0 * ((double)sy[c] * (double)iy + (double)sx[c] * (double)ix);
  }
  #pragma unroll
  for (int off = 32; off >= 1; off >>= 1)
    dis_acc += __shfl_down(dis_acc, off);
  if (lane == 0)
    slots[((b * NCHUNK + chunk) << 2) | w] = dis_acc;           // unique slot

  // ---- cross-wave merge of per-pixel top-2 partials ----
  __syncthreads();
  const int t = threadIdx.x;
  if (t < NF4) {
    float4 mv1 = lm[0][0][t], mv2 = lm[0][1][t], mS = lm[0][2][t];
    #pragma unroll
    for (int ww = 1; ww < 4; ++ww) {
      mergev4(mv1, mv2, lm[ww][0][t], lm[ww][1][t]);
      float4 bS = lm[ww][2][t];
      mS.x += bS.x; mS.y += bS.y; mS.z += bS.z; mS.w += bS.w;
    }
    const int idx = chunk * NPIX4 + b * NF4 + t;
    wsV1[idx] = mv1; wsV2[idx] = mv2; wsS[idx] = mS;
  }
}

// ---------------- merge chunk partials -> div; last block finalizes ----------------
__global__ __launch_bounds__(256) void div_merge_kernel(const float4* __restrict__ wsV1,
    const float4* __restrict__ wsV2, const float4* __restrict__ wsS,
    double* __restrict__ slots, unsigned* __restrict__ counter,
    float* __restrict__ out) {
  const int t = threadIdx.x, lane = t & 63, w = t >> 6;
  const int g = blockIdx.x * 64 + lane;

  float4 a1[4], a2[4], aS[4];
  #pragma unroll
  for (int c = 0; c < 4; ++c) {
    const int idx = (w * 4 + c) * NPIX4 + g;
    a1[c] = wsV1[idx]; a2[c] = wsV2[idx]; aS[c] = wsS[idx];
  }
  float4 v1 = a1[0], v2 = a2[0], S = aS[0];
  #pragma unroll
  for (int c = 1; c < 4; ++c) {
    mergev4(v1, v2, a1[c], a2[c]);
    S.x += aS[c].x; S.y += aS[c].y; S.z += aS[c].z; S.w += aS[c].w;
  }
  __shared__ float4 sm[4][3][64];
  sm[w][0][lane] = v1; sm[w][1][lane] = v2; sm[w][2][lane] = S;
  __syncthreads();

  if (t < 64) {
    v1 = sm[0][0][t]; v2 = sm[0][1][t]; S = sm[0][2][t];
    #pragma unroll
    for (int ww = 1; ww < 4; ++ww) {
      mergev4(v1, v2, sm[ww][0][t], sm[ww][1][t]);
      float4 bS = sm[ww][2][t];
      S.x += bS.x; S.y += bS.y; S.z += bS.z; S.w += bS.w;
    }
    // sum_c loo_c*M_c = clamp(v1)*(S - v1) + clamp(v2)*v1  (per pixel)
    double contrib =
        (double)fmaxf(v1.x, NEG_FILL) * ((double)S.x - (double)v1.x) + (double)fmaxf(v2.x, NEG_FILL) * (double)v1.x
      + (double)fmaxf(v1.y, NEG_FILL) * ((double)S.y - (double)v1.y) + (double)fmaxf(v2.y, NEG_FILL) * (double)v1.y
      + (double)fmaxf(v1.z, NEG_FILL) * ((double)S.z - (double)v1.z) + (double)fmaxf(v2.z, NEG_FILL) * (double)v1.z
      + (double)fmaxf(v1.w, NEG_FILL) * ((double)S.w - (double)v1.w) + (double)fmaxf(v2.w, NEG_FILL) * (double)v1.w;
    #pragma unroll
    for (int off = 32; off >= 1; off >>= 1)
      contrib += __shfl_down(contrib, off);
    if (t == 0)
      slots[DIS_SLOTS + blockIdx.x] = contrib;
  }

  // ---- last-block finalize (ticket) ----
  __shared__ unsigned ticket_s;
  __threadfence();
  __syncthreads();
  if (t == 0) ticket_s = atomicAdd(counter, 1u);
  __syncthreads();
  if (ticket_s == DIV_SLOTS - 1) {
    __threadfence();
    double dis = 0.0;
    #pragma unroll
    for (int i = 0; i < 16; ++i) dis += slots[t + (i << 8)];
    double dv = (t < DIV_SLOTS) ? slots[DIS_SLOTS + t] : 0.0;
    #pragma unroll
    for (int off = 32; off >= 1; off >>= 1) {
      dis += __shfl_down(dis, off);
      dv  += __shfl_down(dv,  off);
    }
    __shared__ double pd[4], pv[4];
    if (lane == 0) { pd[w] = dis; pv[w] = dv; }
    __syncthreads();
    if (t == 0) {
      out[0] = (float)((pd[0] + pd[1] + pd[2] + pd[3]) / NTOT);
      out[1] = (float)((pv[0] + pv[1] + pv[2] + pv[3]) / NTOT);
    }
  }
}

extern "C" void kernel_launch(void* const* d_in, const int* in_sizes, int n_in,
                              void* d_out, int out_size, void* d_ws, size_t ws_size,
                              hipStream_t stream) {
  const float* M = (const float*)d_in[0];
  double*   slots   = (double*)d_ws;                        // 4292 doubles
  unsigned* counter = (unsigned*)((char*)d_ws + 40960);
  float4*   planes  = (float4*)((char*)d_ws + 65536);       // 3 planes of PLANE4 float4
  float4* wsV1 = planes;
  float4* wsV2 = planes + PLANE4;
  float4* wsS  = planes + 2 * (size_t)PLANE4;
  fused_kernel<<<dim3(NCHUNK, BB), 256, 0, stream>>>(M, slots, wsV1, wsV2, wsS, counter);
  div_merge_kernel<<<DIV_SLOTS, 256, 0, stream>>>(wsV1, wsV2, wsS, slots, counter,
                                                  (float*)d_out);
}

// Round 7
// 70.281 us; speedup vs baseline: 1.1221x; 1.1021x over previous
//
#include <hip/hip_runtime.h>
#include <math.h>

// M is (64, 512, 28, 28) fp32.
#define BB 64
#define CC 512
#define HWP 784                 // px per map
#define NF4 196                 // float4 groups per map
#define NCHUNK 16               // channel chunks (32 ch each)
#define NPIX4 12544             // (64*784)/4 float4 pixel-groups
#define PLANE4 200704           // NCHUNK * NPIX4 float4 per plane
#define DIS_SLOTS 4096          // 64 b * 16 chunks * 4 waves
#define DIV_SLOTS 196
#define NEG_FILL -999999.0f
#define NTOT 25690112.0         // 64*512*28*28

static __device__ __forceinline__ unsigned sortable(float v) {
  unsigned b = __float_as_uint(v);
  return (b & 0x80000000u) ? ~b : (b | 0x80000000u);
}
// branchless top-2 insert
static __device__ __forceinline__ void top2(float v, float& v1, float& v2) {
  float lo = fminf(v, v1);
  v1 = fmaxf(v1, v);
  v2 = fmaxf(v2, lo);
}
// merge two (v1>=v2) pairs
static __device__ __forceinline__ void mergev(float& v1, float& v2, float b1, float b2) {
  float lo = fminf(v1, b1);
  v1 = fmaxf(v1, b1);
  v2 = fmaxf(lo, fmaxf(v2, b2));
}
static __device__ __forceinline__ void mergev4(float4& v1, float4& v2, float4 b1, float4 b2) {
  mergev(v1.x, v2.x, b1.x, b2.x);
  mergev(v1.y, v2.y, b1.y, b2.y);
  mergev(v1.z, v2.z, b1.z, b2.z);
  mergev(v1.w, v2.w, b1.w, b2.w);
}

// per-channel consume body (float4 group at pxb, geometry fy/fx*/rr*)
#define CHBODY(c) {                                                          \
    float a0 = d[c].x, a1 = d[c].y, a2 = d[c].z, a3 = d[c].w;                \
    float q0 = a0, q1 = a1, q2 = a2, q3 = a3;                                \
    if (fake) { a0 = a1 = a2 = a3 = 0.f;                                     \
                q0 = q1 = q2 = q3 = -INFINITY; }                             \
    const float sum4 = (a0 + a1) + (a2 + a3);                                \
    s0[c] += sum4;                                                           \
    sy[c] = fmaf(sum4, fy, sy[c]);                                           \
    sx[c] = fmaf(a0, fx0, sx[c]); sx[c] = fmaf(a1, fx1, sx[c]);              \
    sx[c] = fmaf(a2, fx2, sx[c]); sx[c] = fmaf(a3, fx3, sx[c]);              \
    srr = fmaf(a0, rr0, srr); srr = fmaf(a1, rr1, srr);                      \
    srr = fmaf(a2, rr2, srr); srr = fmaf(a3, rr3, srr);                      \
    if (q0 > bv[c]) { bv[c] = q0; bi[c] = pxb;     }                         \
    if (q1 > bv[c]) { bv[c] = q1; bi[c] = pxb + 1; }                         \
    if (q2 > bv[c]) { bv[c] = q2; bi[c] = pxb + 2; }                         \
    if (q3 > bv[c]) { bv[c] = q3; bi[c] = pxb + 3; }                         \
    top2(q0, v1.x, v2.x); S.x += a0;                                         \
    top2(q1, v1.y, v2.y); S.y += a1;                                         \
    top2(q2, v1.z, v2.z); S.z += a2;                                         \
    top2(q3, v1.w, v2.w); S.w += a3; }

#define GEOM(f)                                                              \
    const int y = (f) / 7;                                                   \
    const float fy  = (float)y;                                              \
    const float fx0 = (float)(((f) - y * 7) * 4);                            \
    const float fx1 = fx0 + 1.f, fx2 = fx0 + 2.f, fx3 = fx0 + 3.f;           \
    const float fyy = fy * fy;                                               \
    const float rr0 = fyy + fx0 * fx0, rr1 = fyy + fx1 * fx1;                \
    const float rr2 = fyy + fx2 * fx2, rr3 = fyy + fx3 * fx3;                \
    const int pxb = (f) * 4;

// ---------------- fused single-pass kernel ----------------
// block = (chunk, b): 32 ch x 784 px; 4 waves, 8 ch/wave. float4 passes
// 0..2 uniform + masked tail; rolling half-pass prefetch (d[8] + dn[4]).
// amdgpu_waves_per_eu(4,4): pins EXACTLY 4 waves/EU -> 128-VGPR budget, so the
// allocator stops targeting 64 regs + spilling (rounds 5/6: 90 MB scratch).
// LDS 37.9 KB caps at 4 blocks/CU = 4 waves/EU anyway, so max=4 costs nothing.
__global__
__attribute__((amdgpu_flat_work_group_size(256, 256), amdgpu_waves_per_eu(4, 4)))
void fused_kernel(const float* __restrict__ M,
    double* __restrict__ slots, float4* __restrict__ wsV1, float4* __restrict__ wsV2,
    float4* __restrict__ wsS, unsigned* __restrict__ counter) {
  const int lane  = threadIdx.x & 63;
  const int w     = threadIdx.x >> 6;
  const int chunk = blockIdx.x;
  const int b     = blockIdx.y;
  if (chunk == 0 && b == 0 && threadIdx.x == 0) *counter = 0u;   // for div_merge ticket

  const float4* base4 =
      (const float4*)(M + ((size_t)b * CC + chunk * 32 + w * 8) * HWP);

  float s0[8], sy[8], sx[8], bv[8];
  int bi[8];
  #pragma unroll
  for (int c = 0; c < 8; ++c) { s0[c]=0.f; sy[c]=0.f; sx[c]=0.f; bv[c]=-INFINITY; bi[c]=0; }
  float srr = 0.f;                          // sum M*(y^2+x^2), lane slice

  __shared__ float4 lm[4][3][NF4];          // per-wave per-pixel (v1,v2,S)

  float4 d[8], dn[4];
  #pragma unroll
  for (int c = 0; c < 8; ++c) d[c] = base4[c * NF4 + lane];     // pass-0 loads

  const int tailf = (lane < 4) ? (192 + lane) : 195;            // clamped tail group

  #pragma unroll
  for (int k = 0; k < 3; ++k) {
    const int f  = lane + 64 * k;
    const int nf = (k == 2) ? tailf : (lane + 64 * (k + 1));
    const bool fake = false;
    GEOM(f)
    float4 v1 = make_float4(-INFINITY, -INFINITY, -INFINITY, -INFINITY);
    float4 v2 = v1;
    float4 S  = make_float4(0.f, 0.f, 0.f, 0.f);
    #pragma unroll
    for (int c = 0; c < 4; ++c) dn[c] = base4[c * NF4 + nf];    // prefetch next A-half
    CHBODY(4) CHBODY(5) CHBODY(6) CHBODY(7)                      // consume B-half
    #pragma unroll
    for (int c = 4; c < 8; ++c) d[c] = base4[c * NF4 + nf];     // refill B-half
    CHBODY(0) CHBODY(1) CHBODY(2) CHBODY(3)                      // consume A-half
    #pragma unroll
    for (int c = 0; c < 4; ++c) d[c] = dn[c];                   // rotate A-half
    lm[w][0][f] = v1; lm[w][1][f] = v2; lm[w][2][f] = S;
  }
  { // masked-uniform tail pass (groups 192..195 real on lanes 0..3)
    const int f = tailf;
    const bool fake = (lane >= 4);
    GEOM(f)
    float4 v1 = make_float4(-INFINITY, -INFINITY, -INFINITY, -INFINITY);
    float4 v2 = v1;
    float4 S  = make_float4(0.f, 0.f, 0.f, 0.f);
    CHBODY(0) CHBODY(1) CHBODY(2) CHBODY(3)
    CHBODY(4) CHBODY(5) CHBODY(6) CHBODY(7)
    if (!fake) { lm[w][0][f] = v1; lm[w][1][f] = v2; lm[w][2][f] = S; }
  }

  // ---- dis epilogue: per-channel argmax butterfly, lane-local contribution ----
  double dis_acc = (double)srr;
  #pragma unroll
  for (int c = 0; c < 8; ++c) {
    unsigned long long key =
        ((unsigned long long)sortable(bv[c]) << 32) | (unsigned)(~bi[c]);
    #pragma unroll
    for (int off = 1; off < 64; off <<= 1) {
      unsigned long long o = __shfl_xor(key, off);
      key = (key > o) ? key : o;            // max val; tie -> min px
    }
    const int px = (int)(~((unsigned)key));
    const int iy = px / 28;
    const int ix = px - iy * 28;
    dis_acc += (double)s0[c] * (double)(iy * iy + ix * ix)
             - 2.0 * ((double)sy[c] * (double)iy + (double)sx[c] * (double)ix);
  }
  #pragma unroll
  for (int off = 32; off >= 1; off >>= 1)
    dis_acc += __shfl_down(dis_acc, off);
  if (lane == 0)
    slots[((b * NCHUNK + chunk) << 2) | w] = dis_acc;           // unique slot

  // ---- cross-wave merge of per-pixel top-2 partials ----
  __syncthreads();
  const int t = threadIdx.x;
  if (t < NF4) {
    float4 mv1 = lm[0][0][t], mv2 = lm[0][1][t], mS = lm[0][2][t];
    #pragma unroll
    for (int ww = 1; ww < 4; ++ww) {
      mergev4(mv1, mv2, lm[ww][0][t], lm[ww][1][t]);
      float4 bS = lm[ww][2][t];
      mS.x += bS.x; mS.y += bS.y; mS.z += bS.z; mS.w += bS.w;
    }
    const int idx = chunk * NPIX4 + b * NF4 + t;
    wsV1[idx] = mv1; wsV2[idx] = mv2; wsS[idx] = mS;
  }
}

// ---------------- merge chunk partials -> div; last block finalizes ----------------
__global__ __launch_bounds__(256) void div_merge_kernel(const float4* __restrict__ wsV1,
    const float4* __restrict__ wsV2, const float4* __restrict__ wsS,
    double* __restrict__ slots, unsigned* __restrict__ counter,
    float* __restrict__ out) {
  const int t = threadIdx.x, lane = t & 63, w = t >> 6;
  const int g = blockIdx.x * 64 + lane;

  float4 a1[4], a2[4], aS[4];
  #pragma unroll
  for (int c = 0; c < 4; ++c) {
    const int idx = (w * 4 + c) * NPIX4 + g;
    a1[c] = wsV1[idx]; a2[c] = wsV2[idx]; aS[c] = wsS[idx];
  }
  float4 v1 = a1[0], v2 = a2[0], S = aS[0];
  #pragma unroll
  for (int c = 1; c < 4; ++c) {
    mergev4(v1, v2, a1[c], a2[c]);
    S.x += aS[c].x; S.y += aS[c].y; S.z += aS[c].z; S.w += aS[c].w;
  }
  __shared__ float4 sm[4][3][64];
  sm[w][0][lane] = v1; sm[w][1][lane] = v2; sm[w][2][lane] = S;
  __syncthreads();

  if (t < 64) {
    v1 = sm[0][0][t]; v2 = sm[0][1][t]; S = sm[0][2][t];
    #pragma unroll
    for (int ww = 1; ww < 4; ++ww) {
      mergev4(v1, v2, sm[ww][0][t], sm[ww][1][t]);
      float4 bS = sm[ww][2][t];
      S.x += bS.x; S.y += bS.y; S.z += bS.z; S.w += bS.w;
    }
    // sum_c loo_c*M_c = clamp(v1)*(S - v1) + clamp(v2)*v1  (per pixel)
    double contrib =
        (double)fmaxf(v1.x, NEG_FILL) * ((double)S.x - (double)v1.x) + (double)fmaxf(v2.x, NEG_FILL) * (double)v1.x
      + (double)fmaxf(v1.y, NEG_FILL) * ((double)S.y - (double)v1.y) + (double)fmaxf(v2.y, NEG_FILL) * (double)v1.y
      + (double)fmaxf(v1.z, NEG_FILL) * ((double)S.z - (double)v1.z) + (double)fmaxf(v2.z, NEG_FILL) * (double)v1.z
      + (double)fmaxf(v1.w, NEG_FILL) * ((double)S.w - (double)v1.w) + (double)fmaxf(v2.w, NEG_FILL) * (double)v1.w;
    #pragma unroll
    for (int off = 32; off >= 1; off >>= 1)
      contrib += __shfl_down(contrib, off);
    if (t == 0)
      slots[DIS_SLOTS + blockIdx.x] = contrib;
  }

  // ---- last-block finalize (ticket) ----
  __shared__ unsigned ticket_s;
  __threadfence();
  __syncthreads();
  if (t == 0) ticket_s = atomicAdd(counter, 1u);
  __syncthreads();
  if (ticket_s == DIV_SLOTS - 1) {
    __threadfence();
    double dis = 0.0;
    #pragma unroll
    for (int i = 0; i < 16; ++i) dis += slots[t + (i << 8)];
    double dv = (t < DIV_SLOTS) ? slots[DIS_SLOTS + t] : 0.0;
    #pragma unroll
    for (int off = 32; off >= 1; off >>= 1) {
      dis += __shfl_down(dis, off);
      dv  += __shfl_down(dv,  off);
    }
    __shared__ double pd[4], pv[4];
    if (lane == 0) { pd[w] = dis; pv[w] = dv; }
    __syncthreads();
    if (t == 0) {
      out[0] = (float)((pd[0] + pd[1] + pd[2] + pd[3]) / NTOT);
      out[1] = (float)((pv[0] + pv[1] + pv[2] + pv[3]) / NTOT);
    }
  }
}

extern "C" void kernel_launch(void* const* d_in, const int* in_sizes, int n_in,
                              void* d_out, int out_size, void* d_ws, size_t ws_size,
                              hipStream_t stream) {
  const float* M = (const float*)d_in[0];
  double*   slots   = (double*)d_ws;                        // 4292 doubles
  unsigned* counter = (unsigned*)((char*)d_ws + 40960);
  float4*   planes  = (float4*)((char*)d_ws + 65536);       // 3 planes of PLANE4 float4
  float4* wsV1 = planes;
  float4* wsV2 = planes + PLANE4;
  float4* wsS  = planes + 2 * (size_t)PLANE4;
  fused_kernel<<<dim3(NCHUNK, BB), 256, 0, stream>>>(M, slots, wsV1, wsV2, wsS, counter);
  div_merge_kernel<<<DIV_SLOTS, 256, 0, stream>>>(wsV1, wsV2, wsS, slots, counter,
                                                  (float*)d_out);
}

// Round 8
// 50.422 us; speedup vs baseline: 1.5640x; 1.3938x over previous
//
#include <hip/hip_runtime.h>
#include <math.h>

// M is (64, 512, 28, 28) fp32.
#define BB 64
#define CC 512
#define HWP 784                 // px per map
#define NF4 196                 // float4 groups per map
#define NCHUNK 16               // channel chunks (32 ch each)
#define NPIX4 12544             // (64*784)/4 float4 pixel-groups
#define PLANE4 200704           // NCHUNK * NPIX4 float4 per plane
#define DIS_SLOTS 4096          // 64 b * 16 chunks * 4 waves
#define DIV_SLOTS 196
#define NEG_FILL -999999.0f
#define NTOT 25690112.0         // 64*512*28*28

static __device__ __forceinline__ unsigned sortable(float v) {
  unsigned b = __float_as_uint(v);
  return (b & 0x80000000u) ? ~b : (b | 0x80000000u);
}
// branchless top-2 insert
static __device__ __forceinline__ void top2(float v, float& v1, float& v2) {
  float lo = fminf(v, v1);
  v1 = fmaxf(v1, v);
  v2 = fmaxf(v2, lo);
}
// merge two (v1>=v2) pairs
static __device__ __forceinline__ void mergev(float& v1, float& v2, float b1, float b2) {
  float lo = fminf(v1, b1);
  v1 = fmaxf(v1, b1);
  v2 = fmaxf(lo, fmaxf(v2, b2));
}
static __device__ __forceinline__ void mergev4(float4& v1, float4& v2, float4 b1, float4 b2) {
  mergev(v1.x, v2.x, b1.x, b2.x);
  mergev(v1.y, v2.y, b1.y, b2.y);
  mergev(v1.z, v2.z, b1.z, b2.z);
  mergev(v1.w, v2.w, b1.w, b2.w);
}

// per-channel consume body (float4 group at pxb, geometry fy/fx*/rr*)
#define CHBODY(c) {                                                          \
    float a0 = d[c].x, a1 = d[c].y, a2 = d[c].z, a3 = d[c].w;                \
    float q0 = a0, q1 = a1, q2 = a2, q3 = a3;                                \
    if (fake) { a0 = a1 = a2 = a3 = 0.f;                                     \
                q0 = q1 = q2 = q3 = -INFINITY; }                             \
    const float sum4 = (a0 + a1) + (a2 + a3);                                \
    s0[c] += sum4;                                                           \
    sy[c] = fmaf(sum4, fy, sy[c]);                                           \
    sx[c] = fmaf(a0, fx0, sx[c]); sx[c] = fmaf(a1, fx1, sx[c]);              \
    sx[c] = fmaf(a2, fx2, sx[c]); sx[c] = fmaf(a3, fx3, sx[c]);              \
    srr = fmaf(a0, rr0, srr); srr = fmaf(a1, rr1, srr);                      \
    srr = fmaf(a2, rr2, srr); srr = fmaf(a3, rr3, srr);                      \
    if (q0 > bv[c]) { bv[c] = q0; bi[c] = pxb;     }                         \
    if (q1 > bv[c]) { bv[c] = q1; bi[c] = pxb + 1; }                         \
    if (q2 > bv[c]) { bv[c] = q2; bi[c] = pxb + 2; }                         \
    if (q3 > bv[c]) { bv[c] = q3; bi[c] = pxb + 3; }                         \
    top2(q0, v1.x, v2.x); S.x += a0;                                         \
    top2(q1, v1.y, v2.y); S.y += a1;                                         \
    top2(q2, v1.z, v2.z); S.z += a2;                                         \
    top2(q3, v1.w, v2.w); S.w += a3; }

#define GEOM(f)                                                              \
    const int y = (f) / 7;                                                   \
    const float fy  = (float)y;                                              \
    const float fx0 = (float)(((f) - y * 7) * 4);                            \
    const float fx1 = fx0 + 1.f, fx2 = fx0 + 2.f, fx3 = fx0 + 3.f;           \
    const float fyy = fy * fy;                                               \
    const float rr0 = fyy + fx0 * fx0, rr1 = fyy + fx1 * fx1;                \
    const float rr2 = fyy + fx2 * fx2, rr3 = fyy + fx3 * fx3;                \
    const int pxb = (f) * 4;

// ---------------- fused single-pass kernel ----------------
// block = (chunk, b): 32 ch x 784 px; 4 waves, 8 ch/wave. float4 passes
// 0..2 uniform + masked tail; rolling half-pass prefetch (d[8] + dn[4]).
// NO occupancy hint: every min-occupancy attribute tried (launch_bounds ",4",
// waves_per_eu(4), waves_per_eu(4,4)) made the allocator clamp to 64 VGPRs and
// spill ~78 MB to scratch (rounds 3-7). Bare launch_bounds(256) -> allocator
// sizes to the live set (~115 regs, r2 precedent: 100 regs, zero spill).
// LDS 37.9 KB caps occupancy at 4 blocks/CU anyway.
__global__ __launch_bounds__(256)
void fused_kernel(const float* __restrict__ M,
    double* __restrict__ slots, float4* __restrict__ wsV1, float4* __restrict__ wsV2,
    float4* __restrict__ wsS, unsigned* __restrict__ counter) {
  const int lane  = threadIdx.x & 63;
  const int w     = threadIdx.x >> 6;
  const int chunk = blockIdx.x;
  const int b     = blockIdx.y;
  if (chunk == 0 && b == 0 && threadIdx.x == 0) *counter = 0u;   // for div_merge ticket

  const float4* base4 =
      (const float4*)(M + ((size_t)b * CC + chunk * 32 + w * 8) * HWP);

  float s0[8], sy[8], sx[8], bv[8];
  int bi[8];
  #pragma unroll
  for (int c = 0; c < 8; ++c) { s0[c]=0.f; sy[c]=0.f; sx[c]=0.f; bv[c]=-INFINITY; bi[c]=0; }
  float srr = 0.f;                          // sum M*(y^2+x^2), lane slice

  __shared__ float4 lm[4][3][NF4];          // per-wave per-pixel (v1,v2,S)

  float4 d[8], dn[4];
  #pragma unroll
  for (int c = 0; c < 8; ++c) d[c] = base4[c * NF4 + lane];     // pass-0 loads

  const int tailf = (lane < 4) ? (192 + lane) : 195;            // clamped tail group

  #pragma unroll
  for (int k = 0; k < 3; ++k) {
    const int f  = lane + 64 * k;
    const int nf = (k == 2) ? tailf : (lane + 64 * (k + 1));
    const bool fake = false;
    GEOM(f)
    float4 v1 = make_float4(-INFINITY, -INFINITY, -INFINITY, -INFINITY);
    float4 v2 = v1;
    float4 S  = make_float4(0.f, 0.f, 0.f, 0.f);
    #pragma unroll
    for (int c = 0; c < 4; ++c) dn[c] = base4[c * NF4 + nf];    // prefetch next A-half
    CHBODY(4) CHBODY(5) CHBODY(6) CHBODY(7)                      // consume B-half
    #pragma unroll
    for (int c = 4; c < 8; ++c) d[c] = base4[c * NF4 + nf];     // refill B-half
    CHBODY(0) CHBODY(1) CHBODY(2) CHBODY(3)                      // consume A-half
    #pragma unroll
    for (int c = 0; c < 4; ++c) d[c] = dn[c];                   // rotate A-half
    lm[w][0][f] = v1; lm[w][1][f] = v2; lm[w][2][f] = S;
  }
  { // masked-uniform tail pass (groups 192..195 real on lanes 0..3)
    const int f = tailf;
    const bool fake = (lane >= 4);
    GEOM(f)
    float4 v1 = make_float4(-INFINITY, -INFINITY, -INFINITY, -INFINITY);
    float4 v2 = v1;
    float4 S  = make_float4(0.f, 0.f, 0.f, 0.f);
    CHBODY(0) CHBODY(1) CHBODY(2) CHBODY(3)
    CHBODY(4) CHBODY(5) CHBODY(6) CHBODY(7)
    if (!fake) { lm[w][0][f] = v1; lm[w][1][f] = v2; lm[w][2][f] = S; }
  }

  // ---- dis epilogue: per-channel argmax butterfly, lane-local contribution ----
  double dis_acc = (double)srr;
  #pragma unroll
  for (int c = 0; c < 8; ++c) {
    unsigned long long key =
        ((unsigned long long)sortable(bv[c]) << 32) | (unsigned)(~bi[c]);
    #pragma unroll
    for (int off = 1; off < 64; off <<= 1) {
      unsigned long long o = __shfl_xor(key, off);
      key = (key > o) ? key : o;            // max val; tie -> min px
    }
    const int px = (int)(~((unsigned)key));
    const int iy = px / 28;
    const int ix = px - iy * 28;
    dis_acc += (double)s0[c] * (double)(iy * iy + ix * ix)
             - 2.0 * ((double)sy[c] * (double)iy + (double)sx[c] * (double)ix);
  }
  #pragma unroll
  for (int off = 32; off >= 1; off >>= 1)
    dis_acc += __shfl_down(dis_acc, off);
  if (lane == 0)
    slots[((b * NCHUNK + chunk) << 2) | w] = dis_acc;           // unique slot

  // ---- cross-wave merge of per-pixel top-2 partials ----
  __syncthreads();
  const int t = threadIdx.x;
  if (t < NF4) {
    float4 mv1 = lm[0][0][t], mv2 = lm[0][1][t], mS = lm[0][2][t];
    #pragma unroll
    for (int ww = 1; ww < 4; ++ww) {
      mergev4(mv1, mv2, lm[ww][0][t], lm[ww][1][t]);
      float4 bS = lm[ww][2][t];
      mS.x += bS.x; mS.y += bS.y; mS.z += bS.z; mS.w += bS.w;
    }
    const int idx = chunk * NPIX4 + b * NF4 + t;
    wsV1[idx] = mv1; wsV2[idx] = mv2; wsS[idx] = mS;
  }
}

// ---------------- merge chunk partials -> div; last block finalizes ----------------
__global__ __launch_bounds__(256) void div_merge_kernel(const float4* __restrict__ wsV1,
    const float4* __restrict__ wsV2, const float4* __restrict__ wsS,
    double* __restrict__ slots, unsigned* __restrict__ counter,
    float* __restrict__ out) {
  const int t = threadIdx.x, lane = t & 63, w = t >> 6;
  const int g = blockIdx.x * 64 + lane;

  float4 a1[4], a2[4], aS[4];
  #pragma unroll
  for (int c = 0; c < 4; ++c) {
    const int idx = (w * 4 + c) * NPIX4 + g;
    a1[c] = wsV1[idx]; a2[c] = wsV2[idx]; aS[c] = wsS[idx];
  }
  float4 v1 = a1[0], v2 = a2[0], S = aS[0];
  #pragma unroll
  for (int c = 1; c < 4; ++c) {
    mergev4(v1, v2, a1[c], a2[c]);
    S.x += aS[c].x; S.y += aS[c].y; S.z += aS[c].z; S.w += aS[c].w;
  }
  __shared__ float4 sm[4][3][64];
  sm[w][0][lane] = v1; sm[w][1][lane] = v2; sm[w][2][lane] = S;
  __syncthreads();

  if (t < 64) {
    v1 = sm[0][0][t]; v2 = sm[0][1][t]; S = sm[0][2][t];
    #pragma unroll
    for (int ww = 1; ww < 4; ++ww) {
      mergev4(v1, v2, sm[ww][0][t], sm[ww][1][t]);
      float4 bS = sm[ww][2][t];
      S.x += bS.x; S.y += bS.y; S.z += bS.z; S.w += bS.w;
    }
    // sum_c loo_c*M_c = clamp(v1)*(S - v1) + clamp(v2)*v1  (per pixel)
    double contrib =
        (double)fmaxf(v1.x, NEG_FILL) * ((double)S.x - (double)v1.x) + (double)fmaxf(v2.x, NEG_FILL) * (double)v1.x
      + (double)fmaxf(v1.y, NEG_FILL) * ((double)S.y - (double)v1.y) + (double)fmaxf(v2.y, NEG_FILL) * (double)v1.y
      + (double)fmaxf(v1.z, NEG_FILL) * ((double)S.z - (double)v1.z) + (double)fmaxf(v2.z, NEG_FILL) * (double)v1.z
      + (double)fmaxf(v1.w, NEG_FILL) * ((double)S.w - (double)v1.w) + (double)fmaxf(v2.w, NEG_FILL) * (double)v1.w;
    #pragma unroll
    for (int off = 32; off >= 1; off >>= 1)
      contrib += __shfl_down(contrib, off);
    if (t == 0)
      slots[DIS_SLOTS + blockIdx.x] = contrib;
  }

  // ---- last-block finalize (ticket) ----
  __shared__ unsigned ticket_s;
  __threadfence();
  __syncthreads();
  if (t == 0) ticket_s = atomicAdd(counter, 1u);
  __syncthreads();
  if (ticket_s == DIV_SLOTS - 1) {
    __threadfence();
    double dis = 0.0;
    #pragma unroll
    for (int i = 0; i < 16; ++i) dis += slots[t + (i << 8)];
    double dv = (t < DIV_SLOTS) ? slots[DIS_SLOTS + t] : 0.0;
    #pragma unroll
    for (int off = 32; off >= 1; off >>= 1) {
      dis += __shfl_down(dis, off);
      dv  += __shfl_down(dv,  off);
    }
    __shared__ double pd[4], pv[4];
    if (lane == 0) { pd[w] = dis; pv[w] = dv; }
    __syncthreads();
    if (t == 0) {
      out[0] = (float)((pd[0] + pd[1] + pd[2] + pd[3]) / NTOT);
      out[1] = (float)((pv[0] + pv[1] + pv[2] + pv[3]) / NTOT);
    }
  }
}

extern "C" void kernel_launch(void* const* d_in, const int* in_sizes, int n_in,
                              void* d_out, int out_size, void* d_ws, size_t ws_size,
                              hipStream_t stream) {
  const float* M = (const float*)d_in[0];
  double*   slots   = (double*)d_ws;                        // 4292 doubles
  unsigned* counter = (unsigned*)((char*)d_ws + 40960);
  float4*   planes  = (float4*)((char*)d_ws + 65536);       // 3 planes of PLANE4 float4
  float4* wsV1 = planes;
  float4* wsV2 = planes + PLANE4;
  float4* wsS  = planes + 2 * (size_t)PLANE4;
  fused_kernel<<<dim3(NCHUNK, BB), 256, 0, stream>>>(M, slots, wsV1, wsV2, wsS, counter);
  div_merge_kernel<<<DIV_SLOTS, 256, 0, stream>>>(wsV1, wsV2, wsS, slots, counter,
                                                  (float*)d_out);
}

// Round 9
// 48.418 us; speedup vs baseline: 1.6288x; 1.0414x over previous
//
#include <hip/hip_runtime.h>
#include <math.h>

// M is (64, 512, 28, 28) fp32.
#define BB 64
#define CC 512
#define HWP 784                 // px per map
#define NF4 196                 // float4 groups per map
#define NCHUNK 16               // channel chunks (32 ch each)
#define NPIX4 12544             // (64*784)/4 float4 pixel-groups
#define PLANE4 200704           // NCHUNK * NPIX4 float4 per plane
#define DIS_SLOTS 4096          // 64 b * 16 chunks * 4 waves
#define DIV_SLOTS 196
#define NEG_FILL -999999.0f
#define NTOT 25690112.0         // 64*512*28*28

static __device__ __forceinline__ unsigned sortable(float v) {
  unsigned b = __float_as_uint(v);
  return (b & 0x80000000u) ? ~b : (b | 0x80000000u);
}
// branchless top-2 insert
static __device__ __forceinline__ void top2(float v, float& v1, float& v2) {
  float lo = fminf(v, v1);
  v1 = fmaxf(v1, v);
  v2 = fmaxf(v2, lo);
}
// merge two (v1>=v2) pairs
static __device__ __forceinline__ void mergev(float& v1, float& v2, float b1, float b2) {
  float lo = fminf(v1, b1);
  v1 = fmaxf(v1, b1);
  v2 = fmaxf(lo, fmaxf(v2, b2));
}
static __device__ __forceinline__ void mergev4(float4& v1, float4& v2, float4 b1, float4 b2) {
  mergev(v1.x, v2.x, b1.x, b2.x);
  mergev(v1.y, v2.y, b1.y, b2.y);
  mergev(v1.z, v2.z, b1.z, b2.z);
  mergev(v1.w, v2.w, b1.w, b2.w);
}

// ---------------- fused single-pass kernel ----------------
// block = (chunk, b): 32 ch x 784 px; 4 waves, 8 ch/wave.
// r3-proven inner loop: per position-pass, issue 8 float4 loads then consume;
// compiler emits progressive vmcnt(7..0) so compute overlaps remaining loads.
// NO occupancy attribute (r2/r8 precedent): allocator sizes to live set
// (~100 VGPR), zero spill. Any min-occupancy hint clamps to 64 VGPR + ~78 MB
// scratch spill (measured rounds 3-7). LDS 37.6 KB caps 4 blocks/CU anyway.
__global__ __launch_bounds__(256)
void fused_kernel(const float* __restrict__ M,
    double* __restrict__ slots, float4* __restrict__ wsV1, float4* __restrict__ wsV2,
    float4* __restrict__ wsS, unsigned* __restrict__ counter) {
  const int lane  = threadIdx.x & 63;
  const int w     = threadIdx.x >> 6;
  const int chunk = blockIdx.x;
  const int b     = blockIdx.y;
  if (chunk == 0 && b == 0 && threadIdx.x == 0) *counter = 0u;   // ticket reset

  const float* base = M + ((size_t)b * CC + chunk * 32 + w * 8) * HWP;

  float s0[8], sy[8], sx[8], bv[8];
  int bi[8];
  #pragma unroll
  for (int c = 0; c < 8; ++c) { s0[c]=0.f; sy[c]=0.f; sx[c]=0.f; bv[c]=-INFINITY; bi[c]=0; }
  float srr = 0.f;                          // sum M*(y^2+x^2), lane slice

  __shared__ float4 lm[4][3][NF4];          // per-wave per-pixel (v1,v2,S)

  auto process = [&](int f) {
    const int y  = f / 7;                   // 4|28: all 4 px of a float4 share y
    const float fy  = (float)y;
    const float fx0 = (float)((f - y * 7) * 4);
    const float fx1 = fx0 + 1.f, fx2 = fx0 + 2.f, fx3 = fx0 + 3.f;
    const float fyy = fy * fy;
    const float rr0 = fyy + fx0*fx0, rr1 = fyy + fx1*fx1;
    const float rr2 = fyy + fx2*fx2, rr3 = fyy + fx3*fx3;
    const int pxb = f * 4;

    float4 d[8];
    #pragma unroll
    for (int c = 0; c < 8; ++c)
      d[c] = *(const float4*)(base + c * HWP + pxb);

    const float NI = -INFINITY;
    float4 v1 = make_float4(NI, NI, NI, NI);
    float4 v2 = v1;
    float4 S  = make_float4(0.f, 0.f, 0.f, 0.f);

    #pragma unroll
    for (int c = 0; c < 8; ++c) {
      const float a0 = d[c].x, a1 = d[c].y, a2 = d[c].z, a3 = d[c].w;
      const float sum4 = (a0 + a1) + (a2 + a3);
      s0[c] += sum4;
      sy[c] = fmaf(sum4, fy, sy[c]);                 // shared y
      sx[c] = fmaf(a0, fx0, sx[c]); sx[c] = fmaf(a1, fx1, sx[c]);
      sx[c] = fmaf(a2, fx2, sx[c]); sx[c] = fmaf(a3, fx3, sx[c]);
      srr = fmaf(a0, rr0, srr); srr = fmaf(a1, rr1, srr);
      srr = fmaf(a2, rr2, srr); srr = fmaf(a3, rr3, srr);
      if (a0 > bv[c]) { bv[c] = a0; bi[c] = pxb;     }
      if (a1 > bv[c]) { bv[c] = a1; bi[c] = pxb + 1; }
      if (a2 > bv[c]) { bv[c] = a2; bi[c] = pxb + 2; }
      if (a3 > bv[c]) { bv[c] = a3; bi[c] = pxb + 3; }
      top2(a0, v1.x, v2.x); S.x += a0;
      top2(a1, v1.y, v2.y); S.y += a1;
      top2(a2, v1.z, v2.z); S.z += a2;
      top2(a3, v1.w, v2.w); S.w += a3;
    }
    lm[w][0][f] = v1; lm[w][1][f] = v2; lm[w][2][f] = S;
  };

  #pragma unroll
  for (int k = 0; k < 3; ++k) process(lane + 64 * k);
  if (lane < 4) process(192 + lane);        // exec-masked tail (cheap loads)

  // ---- dis epilogue: per-channel argmax butterfly, lane-local contribution ----
  double dis_acc = (double)srr;
  #pragma unroll
  for (int c = 0; c < 8; ++c) {
    unsigned long long key =
        ((unsigned long long)sortable(bv[c]) << 32) | (unsigned)(~bi[c]);
    #pragma unroll
    for (int off = 1; off < 64; off <<= 1) {
      unsigned long long o = __shfl_xor(key, off);
      key = (key > o) ? key : o;            // max val; tie -> min px
    }
    const int px = (int)(~((unsigned)key));
    const int iy = px / 28;
    const int ix = px - iy * 28;
    dis_acc += (double)s0[c] * (double)(iy * iy + ix * ix)
             - 2.0 * ((double)sy[c] * (double)iy + (double)sx[c] * (double)ix);
  }
  #pragma unroll
  for (int off = 32; off >= 1; off >>= 1)
    dis_acc += __shfl_down(dis_acc, off);
  if (lane == 0)
    slots[((b * NCHUNK + chunk) << 2) | w] = dis_acc;   // unique slot, plain store

  // ---- cross-wave merge of per-pixel top-2 partials ----
  __syncthreads();
  const int t = threadIdx.x;
  if (t < NF4) {
    float4 mv1 = lm[0][0][t], mv2 = lm[0][1][t], mS = lm[0][2][t];
    #pragma unroll
    for (int ww = 1; ww < 4; ++ww) {
      mergev4(mv1, mv2, lm[ww][0][t], lm[ww][1][t]);
      float4 bS = lm[ww][2][t];
      mS.x += bS.x; mS.y += bS.y; mS.z += bS.z; mS.w += bS.w;
    }
    const int idx = chunk * NPIX4 + b * NF4 + t;
    wsV1[idx] = mv1; wsV2[idx] = mv2; wsS[idx] = mS;
  }
}

// ---------------- merge chunk partials -> div; last block finalizes ----------------
__global__ __launch_bounds__(256) void div_merge_kernel(const float4* __restrict__ wsV1,
    const float4* __restrict__ wsV2, const float4* __restrict__ wsS,
    double* __restrict__ slots, unsigned* __restrict__ counter,
    float* __restrict__ out) {
  const int t = threadIdx.x, lane = t & 63, w = t >> 6;
  const int g = blockIdx.x * 64 + lane;

  float4 a1[4], a2[4], aS[4];
  #pragma unroll
  for (int c = 0; c < 4; ++c) {
    const int idx = (w * 4 + c) * NPIX4 + g;
    a1[c] = wsV1[idx]; a2[c] = wsV2[idx]; aS[c] = wsS[idx];
  }
  float4 v1 = a1[0], v2 = a2[0], S = aS[0];
  #pragma unroll
  for (int c = 1; c < 4; ++c) {
    mergev4(v1, v2, a1[c], a2[c]);
    S.x += aS[c].x; S.y += aS[c].y; S.z += aS[c].z; S.w += aS[c].w;
  }
  __shared__ float4 sm[4][3][64];
  sm[w][0][lane] = v1; sm[w][1][lane] = v2; sm[w][2][lane] = S;
  __syncthreads();

  if (t < 64) {
    v1 = sm[0][0][t]; v2 = sm[0][1][t]; S = sm[0][2][t];
    #pragma unroll
    for (int ww = 1; ww < 4; ++ww) {
      mergev4(v1, v2, sm[ww][0][t], sm[ww][1][t]);
      float4 bS = sm[ww][2][t];
      S.x += bS.x; S.y += bS.y; S.z += bS.z; S.w += bS.w;
    }
    // sum_c loo_c*M_c = clamp(v1)*(S - v1) + clamp(v2)*v1  (per pixel)
    double contrib =
        (double)fmaxf(v1.x, NEG_FILL) * ((double)S.x - (double)v1.x) + (double)fmaxf(v2.x, NEG_FILL) * (double)v1.x
      + (double)fmaxf(v1.y, NEG_FILL) * ((double)S.y - (double)v1.y) + (double)fmaxf(v2.y, NEG_FILL) * (double)v1.y
      + (double)fmaxf(v1.z, NEG_FILL) * ((double)S.z - (double)v1.z) + (double)fmaxf(v2.z, NEG_FILL) * (double)v1.z
      + (double)fmaxf(v1.w, NEG_FILL) * ((double)S.w - (double)v1.w) + (double)fmaxf(v2.w, NEG_FILL) * (double)v1.w;
    #pragma unroll
    for (int off = 32; off >= 1; off >>= 1)
      contrib += __shfl_down(contrib, off);
    if (t == 0)
      slots[DIS_SLOTS + blockIdx.x] = contrib;
  }

  // ---- last-block finalize (ticket) ----
  __shared__ unsigned ticket_s;
  __threadfence();
  __syncthreads();
  if (t == 0) ticket_s = atomicAdd(counter, 1u);
  __syncthreads();
  if (ticket_s == DIV_SLOTS - 1) {
    __threadfence();
    double dis = 0.0;
    #pragma unroll
    for (int i = 0; i < 16; ++i) dis += slots[t + (i << 8)];
    double dv = (t < DIV_SLOTS) ? slots[DIS_SLOTS + t] : 0.0;
    #pragma unroll
    for (int off = 32; off >= 1; off >>= 1) {
      dis += __shfl_down(dis, off);
      dv  += __shfl_down(dv,  off);
    }
    __shared__ double pd[4], pv[4];
    if (lane == 0) { pd[w] = dis; pv[w] = dv; }
    __syncthreads();
    if (t == 0) {
      out[0] = (float)((pd[0] + pd[1] + pd[2] + pd[3]) / NTOT);
      out[1] = (float)((pv[0] + pv[1] + pv[2] + pv[3]) / NTOT);
    }
  }
}

extern "C" void kernel_launch(void* const* d_in, const int* in_sizes, int n_in,
                              void* d_out, int out_size, void* d_ws, size_t ws_size,
                              hipStream_t stream) {
  const float* M = (const float*)d_in[0];
  double*   slots   = (double*)d_ws;                        // 4292 doubles
  unsigned* counter = (unsigned*)((char*)d_ws + 40960);
  float4*   planes  = (float4*)((char*)d_ws + 65536);       // 3 planes of PLANE4 float4
  float4* wsV1 = planes;
  float4* wsV2 = planes + PLANE4;
  float4* wsS  = planes + 2 * (size_t)PLANE4;
  fused_kernel<<<dim3(NCHUNK, BB), 256, 0, stream>>>(M, slots, wsV1, wsV2, wsS, counter);
  div_merge_kernel<<<DIV_SLOTS, 256, 0, stream>>>(wsV1, wsV2, wsS, slots, counter,
                                                  (float*)d_out);
}